// Round 9
// baseline (336.408 us; speedup 1.0000x reference)
//
#include <hip/hip_runtime.h>
#include <cstdint>
#include <cstddef>

// ---------------------------------------------------------------------------
// EnzymeCompoundCrossAttention — R11 (resubmit; prior run was an infra
// failure, kernel re-audited): q-split se/pe score (full 512-k row per
// block) -> Sc/colsum2/l eliminated. es/ep unchanged as own kernel.
//
// Algebra (R1/R2/R4 verified):
//   score = x_q (Wq Wk^T) x_k^T / S + (x_k . (Wk bq)) / S   (+iw bias; bk and
//   q-constant terms cancel in softmax).
//   All big GEMMs collapse into Y = enz @ W3 with W3t [768 x 1280]:
//   rows [0,256)=M_big^T, [256,512)=M_se, [512,768)=M_pe.  Y [16384 x 768].
//   Bias terms: t_se/t_pe[row] = dot(enz[row,:], u_{s,p}) * S^-1 (fold_w3);
//   t_es/t_ep[b,k] = dot(x_k, u_e) * S^-1 (fold_w3).
//   Score GEMMs contract over d_cpd=256.
//   out_quarter = (1/Lq) * (wsum @ X_kv) @ Wv + bv.
// Launches: prep -> fold -> y_gemm -> score_esep -> score_sepe -> wx -> out.
// ---------------------------------------------------------------------------

#define SCALE_INV 0.044194173824159216f  // 1/sqrt(512)

typedef short bf16x8 __attribute__((ext_vector_type(8)));
typedef float f32x4  __attribute__((ext_vector_type(4)));

__device__ __forceinline__ ushort f2bf(float f) {
  union { float f; unsigned u; } c; c.f = f;
  unsigned u = c.u + 0x7fffu + ((c.u >> 16) & 1u);
  return (ushort)(u >> 16);
}
__device__ __forceinline__ float bf2f(ushort h) {
  return __uint_as_float(((unsigned)h) << 16);
}
__device__ __forceinline__ void gload16(const ushort* g, ushort* l) {
  __builtin_amdgcn_global_load_lds(
      (const __attribute__((address_space(1))) void*)g,
      (__attribute__((address_space(3))) void*)l, 16, 0, 0);
}

// ---------------------------------------------------------------------------
// Kernel 1: prep — segmented flat grid. Grid 13328.
//   [0,10240)      cvt enz f32->bf16
//   [10240,10752)  cvt sub
//   [10752,11264)  cvt prod
//   [11264,12416)  cvt 6 weight mats to bf16
//   [12416,12592)  u vectors -> f32 scaled
//   [12592,13072)  zero 122880 floats (wsum_es/ep/se/pe + wx_se/pe)
//   [13072,13328)  out init = bias
// ---------------------------------------------------------------------------
__device__ __forceinline__ void cvt8(const float* __restrict__ in,
                                     ushort* __restrict__ out, int blk, int n) {
  int i = (blk * 256 + (int)threadIdx.x) * 8;
  if (i >= n) return;
  float4 a = *(const float4*)(in + i);
  float4 b = *(const float4*)(in + i + 4);
  ushort o[8] = { f2bf(a.x), f2bf(a.y), f2bf(a.z), f2bf(a.w),
                  f2bf(b.x), f2bf(b.y), f2bf(b.z), f2bf(b.w) };
  *(uint4*)(out + i) = *(uint4*)o;
}

__global__ __launch_bounds__(256) void prep_fused(
    const float* __restrict__ enz, const float* __restrict__ sub,
    const float* __restrict__ prod,
    ushort* __restrict__ enz_b, ushort* __restrict__ sub_b, ushort* __restrict__ prod_b,
    const float* __restrict__ enz_Wq, const float* __restrict__ enz_Wk,
    const float* __restrict__ sub_Wq, const float* __restrict__ sub_Wk,
    const float* __restrict__ prod_Wq, const float* __restrict__ prod_Wk,
    ushort* __restrict__ eWq_b, ushort* __restrict__ eWk_b,
    ushort* __restrict__ sWq_b, ushort* __restrict__ sWk_b,
    ushort* __restrict__ pWq_b, ushort* __restrict__ pWk_b,
    const float* __restrict__ enz_bq, const float* __restrict__ sub_bq,
    const float* __restrict__ prod_bq,
    const float* __restrict__ enz_bv, const float* __restrict__ sub_bv,
    const float* __restrict__ prod_bv,
    float* __restrict__ u_s_s, float* __restrict__ u_p_s,
    float* __restrict__ u_e_s,
    float* __restrict__ zero_base, float* __restrict__ out)
{
  const int f = blockIdx.x, t = threadIdx.x;
  if (f < 10240) { cvt8(enz, enz_b, f, 20971520); return; }
  if (f < 10752) { cvt8(sub, sub_b, f - 10240, 1048576); return; }
  if (f < 11264) { cvt8(prod, prod_b, f - 10752, 1048576); return; }
  if (f < 12416) {
    const int l = f - 11264;
    if (l < 320)       cvt8(enz_Wq,  eWq_b, l,        655360);
    else if (l < 640)  cvt8(sub_Wk,  sWk_b, l - 320,  655360);
    else if (l < 960)  cvt8(prod_Wk, pWk_b, l - 640,  655360);
    else if (l < 1024) cvt8(enz_Wk,  eWk_b, l - 960,  131072);
    else if (l < 1088) cvt8(sub_Wq,  sWq_b, l - 1024, 131072);
    else               cvt8(prod_Wq, pWq_b, l - 1088, 131072);
    return;
  }
  if (f < 12592) {
    // u[d] = dot(Wk[d,:512], bq) * SCALE_INV. 16 rows/block, 16 threads/row.
    const int g = f - 12416;
    const float* W; const float* bv; float* U; int d0;
    if (g < 80)       { W = sub_Wk;  bv = sub_bq;  U = u_s_s; d0 = g * 16; }
    else if (g < 160) { W = prod_Wk; bv = prod_bq; U = u_p_s; d0 = (g - 80) * 16; }
    else              { W = enz_Wk;  bv = enz_bq;  U = u_e_s; d0 = (g - 160) * 16; }
    const int r = t >> 4, i = t & 15, d = d0 + r;
    const float* row = W + (size_t)d * 512;
    float s = 0.f;
#pragma unroll
    for (int j = 0; j < 32; j++) s += row[i + j * 16] * bv[i + j * 16];
    s += __shfl_xor(s, 1); s += __shfl_xor(s, 2);
    s += __shfl_xor(s, 4); s += __shfl_xor(s, 8);
    if (i == 0) U[d] = s * SCALE_INV;
    return;
  }
  if (f < 13072) { zero_base[(f - 12592) * 256 + t] = 0.f; return; }
  {
    const int idx = (f - 13072) * 256 + t;  // < 65536 = 32*2048
    const int col = idx & 2047;
    const int q = col >> 9, n = col & 511;
    const float* bvp = (q == 1) ? sub_bv : (q == 3) ? prod_bv : enz_bv;
    out[idx] = bvp[n];
  }
}

// ---------------------------------------------------------------------------
// MFMA tile core v2: 128x128, BK=64, T2 both-sides XOR swizzle.
// ---------------------------------------------------------------------------
__device__ __forceinline__ void mfma_tile64(
    const ushort* __restrict__ A, int lda,
    const ushort* __restrict__ Bt, int ldb, int K,
    int bm, int bn, ushort* AsBase, ushort* BsBase, f32x4 (&acc)[4][4])
{
  const int t = threadIdx.x, wave = t >> 6, lane = t & 63;
  const int r8 = lane >> 3;
  const int csrc = 8 * ((lane & 7) ^ r8);       // pre-swizzled source col
  const int wm = (wave >> 1) * 64, wn = (wave & 1) * 64;
  const int fl = lane & 15, fq = lane >> 4;
  for (int k0 = 0; k0 < K; k0 += 64) {
    __syncthreads();
#pragma unroll
    for (int i = 0; i < 4; i++) {
      const int row = i * 32 + wave * 8 + r8;
      ushort* dst = AsBase + row * 64 + (lane & 7) * 8;
      gload16(A + (size_t)(bm + row) * lda + k0 + csrc, dst);
      gload16(Bt + (size_t)(bn + row) * ldb + k0 + csrc,
              BsBase + row * 64 + (lane & 7) * 8);
    }
    __syncthreads();
#pragma unroll
    for (int kk = 0; kk < 2; kk++) {
      bf16x8 bfr[4];
#pragma unroll
      for (int j = 0; j < 4; j++) {
        const int row = wn + j * 16 + fl;
        bfr[j] = *(const bf16x8*)(BsBase + row * 64 +
                                  8 * (((kk << 2) + fq) ^ (row & 7)));
      }
#pragma unroll
      for (int i = 0; i < 4; i++) {
        const int row = wm + i * 16 + fl;
        bf16x8 af = *(const bf16x8*)(AsBase + row * 64 +
                                     8 * (((kk << 2) + fq) ^ (row & 7)));
#pragma unroll
        for (int j = 0; j < 4; j++)
          acc[i][j] = __builtin_amdgcn_mfma_f32_16x16x32_bf16(af, bfr[j], acc[i][j], 0, 0, 0);
      }
    }
  }
}

// ---------------------------------------------------------------------------
// Kernel 2: fold — grid 332.
//   [0,60):    W3t rows 0..767 via 3 MFMA GEMMs, K=512.
//   [60,76):   t_es/t_ep[b*128+k] = dot(X[k,:], u_e_s).
//   [76,332):  t_se/t_pe[row] = dot(enz_b[row,:], u_{s,p}_s). 64 rows/block.
// ---------------------------------------------------------------------------
__global__ __launch_bounds__(256) void fold_w3(
    const ushort* __restrict__ eWq_b, const ushort* __restrict__ eWk_b,
    const ushort* __restrict__ sWq_b, const ushort* __restrict__ sWk_b,
    const ushort* __restrict__ pWq_b, const ushort* __restrict__ pWk_b,
    const ushort* __restrict__ sub_b, const ushort* __restrict__ prod_b,
    const ushort* __restrict__ enz_b,
    const float* __restrict__ u_e_s, const float* __restrict__ u_s_s,
    const float* __restrict__ u_p_s,
    ushort* __restrict__ W3t, float* __restrict__ t_es, float* __restrict__ t_ep,
    float* __restrict__ t_se, float* __restrict__ t_pe)
{
  __shared__ __align__(16) ushort As[128 * 64];
  __shared__ __align__(16) ushort Bs[128 * 64];
  __shared__ float us[256];
  __shared__ float us2[2][1280];
  const int f = blockIdx.x, t = threadIdx.x;
  if (f >= 76) {
    const int g2 = f - 76;          // [0,256)
    for (int i = t; i < 1280; i += 256) { us2[0][i] = u_s_s[i]; us2[1][i] = u_p_s[i]; }
    __syncthreads();
    const int row = g2 * 64 + (t >> 2), lane4 = t & 3;
    const ushort* xr = enz_b + (size_t)row * 1280;
    float ss = 0.f, sp = 0.f;
#pragma unroll
    for (int q = 0; q < 40; ++q) {
      const int c0 = q * 32 + lane4 * 8;
      bf16x8 v = *(const bf16x8*)(xr + c0);
#pragma unroll
      for (int i = 0; i < 8; ++i) {
        const float x = bf2f((ushort)v[i]);
        ss += x * us2[0][c0 + i];
        sp += x * us2[1][c0 + i];
      }
    }
    ss += __shfl_xor(ss, 1); ss += __shfl_xor(ss, 2);
    sp += __shfl_xor(sp, 1); sp += __shfl_xor(sp, 2);
    if (lane4 == 0) { t_se[row] = ss; t_pe[row] = sp; }
    return;
  }
  if (f >= 60) {
    const int g = f - 60, path = g >> 3, blk8 = g & 7;
    const ushort* Xb = path ? prod_b : sub_b;
    float* T = path ? t_ep : t_es;
    us[t] = u_e_s[t];
    __syncthreads();
#pragma unroll
    for (int e = 0; e < 2; ++e) {
      const int row = blk8 * 512 + e * 256 + t;   // (b*128+k) flat, < 4096
      const ushort* xr = Xb + (size_t)row * 256;
      float s = 0.f;
      for (int c = 0; c < 256; c += 8) {
        bf16x8 v = *(const bf16x8*)(xr + c);
#pragma unroll
        for (int i = 0; i < 8; ++i) s += bf2f((ushort)v[i]) * us[c + i];
      }
      T[row] = s;
    }
    return;
  }
  const int seg = f / 20, l = f % 20;
  const int bm = (l / 10) * 128, bn = (l % 10) * 128;
  const ushort* A  = (seg == 0) ? eWk_b : (seg == 1) ? sWq_b : pWq_b;
  const ushort* Bt = (seg == 0) ? eWq_b : (seg == 1) ? sWk_b : pWk_b;
  f32x4 acc[4][4] = {};
  mfma_tile64(A, 512, Bt, 512, 512, bm, bn, As, Bs, acc);
  const int lane = t & 63, wave = t >> 6;
  const int wm = (wave >> 1) * 64, wn = (wave & 1) * 64;
  const int fl = lane & 15, fq = lane >> 4;
#pragma unroll
  for (int i = 0; i < 4; i++)
#pragma unroll
    for (int j = 0; j < 4; j++) {
      const int col = bn + wn + j * 16 + fl;
#pragma unroll
      for (int r = 0; r < 4; r++) {
        const int row = seg * 256 + bm + wm + i * 16 + fq * 4 + r;
        W3t[(size_t)row * 1280 + col] = f2bf(acc[i][j][r]);
      }
    }
}

// ---------------------------------------------------------------------------
// Kernel 3: Y = enz @ W3  (M=16384, N=768, K=1280).
// BM=128 BN=192 BK=64, 8 waves, dbuf 80 KiB LDS, 2 blocks/CU,
// T2 swizzle + counted vmcnt(2) + setprio.
// ---------------------------------------------------------------------------
__device__ __forceinline__ void yg_stage_unit(
    const ushort* __restrict__ gbase, int k0, int u,
    ushort* ldsTile, int wv, int l, int srow8, int scol)
{
  const int row0 = u * 64 + wv * 8 + srow8;
  gload16(gbase + (size_t)row0 * 1280 + k0 + scol,
          ldsTile + u * 4096 + wv * 512 + l * 8);
}

__device__ __forceinline__ bf16x8 yg_frag(const ushort* tile, int row, int kk, int fq) {
  const int X = (kk * 64 + fq * 16) ^ ((row & 7) << 4);
  return *(const bf16x8*)((const char*)tile + row * 128 + X);
}

__global__ __launch_bounds__(512, 4) void y_gemm(
    const ushort* __restrict__ A,      // enz_b [16384][1280]
    const ushort* __restrict__ B,      // W3t   [768][1280]
    ushort* __restrict__ Y)            // [16384][768]
{
  extern __shared__ __align__(16) ushort lds[];
  const int t = threadIdx.x;
  const int wv = t >> 6, l = t & 63;
  const int fl = l & 15, fq = l >> 4;
  const int f = blockIdx.x;
  const int xcd = f & 7, slot = f >> 3;              // slot in [0,64)
  const int mt = xcd * 16 + (slot >> 2), nt = slot & 3;
  const int bm = mt * 128, bn = nt * 192;
  const int wm = (wv >> 2) * 64, wn = (wv & 3) * 48;
  const int srow8 = l >> 3;
  const int scol = 8 * ((l & 7) ^ srow8);     // inverse-swizzled source col
  const ushort* Ag = A + (size_t)bm * 1280;
  const ushort* Bg = B + (size_t)bn * 1280;

  ushort* A0 = lds;              //  8192 elems (128x64)
  ushort* B0 = lds + 8192;       // 12288 elems (192x64)
  ushort* A1 = lds + 20480;
  ushort* B1 = lds + 28672;      // total 40960 elems = 80 KiB

  f32x4 acc[4][3] = {};

  // ---- prologue: tile0 fully + tile1 A ----
#pragma unroll
  for (int u = 0; u < 2; ++u) yg_stage_unit(Ag, 0, u, A0, wv, l, srow8, scol);
#pragma unroll
  for (int u = 0; u < 3; ++u) yg_stage_unit(Bg, 0, u, B0, wv, l, srow8, scol);
#pragma unroll
  for (int u = 0; u < 2; ++u) yg_stage_unit(Ag, 64, u, A1, wv, l, srow8, scol);
  asm volatile("s_waitcnt vmcnt(2)" ::: "memory");
  __builtin_amdgcn_s_barrier();
  __builtin_amdgcn_sched_barrier(0);

  for (int j = 0; j < 20; ++j) {
    const int p = j & 1;
    const ushort* At = p ? A1 : A0;
    const ushort* Bt = p ? B1 : B0;
    ushort* Bo = p ? B0 : B1;
    const int kn = (j + 1) * 64;

    bf16x8 bf_[3][2];
#pragma unroll
    for (int n = 0; n < 3; ++n)
#pragma unroll
      for (int kk = 0; kk < 2; ++kk)
        bf_[n][kk] = yg_frag(Bt, wn + n * 16 + fl, kk, fq);

#pragma unroll
    for (int mp = 0; mp < 4; ++mp) {
      if (mp < 3 && j < 19) yg_stage_unit(Bg, kn, mp, Bo, wv, l, srow8, scol);
      bf16x8 a0[2];
#pragma unroll
      for (int kk = 0; kk < 2; ++kk)
        a0[kk] = yg_frag(At, wm + mp * 16 + fl, kk, fq);
      __builtin_amdgcn_s_setprio(1);
#pragma unroll
      for (int kk = 0; kk < 2; ++kk)
#pragma unroll
        for (int n = 0; n < 3; ++n)
          acc[mp][n] = __builtin_amdgcn_mfma_f32_16x16x32_bf16(
              a0[kk], bf_[n][kk], acc[mp][n], 0, 0, 0);
      __builtin_amdgcn_s_setprio(0);
    }

    // ---- boundary: release buf, stage A(j+2) into it, counted wait ----
    asm volatile("" ::: "memory");
    __builtin_amdgcn_s_barrier();
    if (j + 2 < 20) {
      ushort* Ao = (ushort*)At;
#pragma unroll
      for (int u = 0; u < 2; ++u)
        yg_stage_unit(Ag, (j + 2) * 64, u, Ao, wv, l, srow8, scol);
    }
    if (j < 18) asm volatile("s_waitcnt vmcnt(2)" ::: "memory");
    else        asm volatile("s_waitcnt vmcnt(0)" ::: "memory");
    __builtin_amdgcn_s_barrier();
    __builtin_amdgcn_sched_barrier(0);
  }

  // ---- epilogue: C-write ----
#pragma unroll
  for (int m = 0; m < 4; ++m)
#pragma unroll
    for (int n = 0; n < 3; ++n)
#pragma unroll
      for (int r = 0; r < 4; ++r) {
        const int row = bm + wm + m * 16 + fq * 4 + r;
        const int col = bn + wn + n * 16 + fl;
        Y[(size_t)row * 768 + col] = f2bf(acc[m][n][r]);
      }
}

// ---------------------------------------------------------------------------
// Kernel 4: es/ep score. Grid 256, 256 thr. C[k=row(128), q=col 128-tile];
// iw read coalesced; full softmax in-block; atomicAdd wsum.
// ---------------------------------------------------------------------------
__global__ __launch_bounds__(256) void score_esep(
    const ushort* __restrict__ Y, const ushort* __restrict__ sub_b,
    const ushort* __restrict__ prod_b, const float* __restrict__ iw,
    const float* __restrict__ t_es, const float* __restrict__ t_ep,
    float* __restrict__ wsum_es, float* __restrict__ wsum_ep)
{
  __shared__ __align__(16) ushort As[128 * 64];
  __shared__ __align__(16) ushort Bs[128 * 64];
  __shared__ float red[2][128];
  __shared__ float red2[2][128];
  const int f = blockIdx.x, t = threadIdx.x;
  const int lane = t & 63, wave = t >> 6;
  const int wm = (wave >> 1) * 64, wn = (wave & 1) * 64;
  const int fl = lane & 15, fq = lane >> 4;
  f32x4 acc[4][4] = {};

  const int path = f >> 7, l = f & 127, b = l & 31, qt = l >> 5;
  const int bn = qt * 128;
  const ushort* X  = (path ? prod_b : sub_b) + (size_t)b * 32768;
  const ushort* Yb = Y + (size_t)b * 512 * 768;
  mfma_tile64(X, 256, Yb, 768, 256, 0, bn, As, Bs, acc);
  const size_t ib = (size_t)b * 65536;
  const float* Tp = (path ? t_ep : t_es) + b * 128;
  float tvv[4][4];
#pragma unroll
  for (int i = 0; i < 4; i++)
#pragma unroll
    for (int r = 0; r < 4; r++) tvv[i][r] = Tp[wm + i * 16 + fq * 4 + r];
  float csum[4] = { 0.f, 0.f, 0.f, 0.f };
#pragma unroll
  for (int i = 0; i < 4; i++)
#pragma unroll
    for (int j = 0; j < 4; j++)
#pragma unroll
      for (int r = 0; r < 4; r++) {
        const int row = wm + i * 16 + fq * 4 + r;   // k (global, Lk=128)
        const int col = wn + j * 16 + fl;           // local q
        float s = acc[i][j][r] * SCALE_INV + tvv[i][r];
        if (path == 0) s += iw[ib + (size_t)row * 512 + (bn + col)];
        const float e = __expf(s);
        acc[i][j][r] = e;
        csum[j] += e;
      }
  // column (q) sums -> softmax denominators (full: all 128 k in-block)
#pragma unroll
  for (int m = 16; m <= 32; m <<= 1)
#pragma unroll
    for (int j = 0; j < 4; j++) csum[j] += __shfl_xor(csum[j], m);
  if (fq == 0)
#pragma unroll
    for (int j = 0; j < 4; j++) red[wave >> 1][wn + j * 16 + fl] = csum[j];
  __syncthreads();
  float invc[4];
#pragma unroll
  for (int j = 0; j < 4; j++) {
    const int col = wn + j * 16 + fl;
    invc[j] = 1.f / (red[0][col] + red[1][col]);
  }
  float rsum[4][4];
#pragma unroll
  for (int i = 0; i < 4; i++)
#pragma unroll
    for (int r = 0; r < 4; r++) rsum[i][r] = 0.f;
#pragma unroll
  for (int i = 0; i < 4; i++)
#pragma unroll
    for (int j = 0; j < 4; j++)
#pragma unroll
      for (int r = 0; r < 4; r++) rsum[i][r] += acc[i][j][r] * invc[j];
#pragma unroll
  for (int m = 1; m <= 8; m <<= 1)
#pragma unroll
    for (int i = 0; i < 4; i++)
#pragma unroll
      for (int r = 0; r < 4; r++)
        rsum[i][r] += __shfl_xor(rsum[i][r], m);
  if (fl == 0)
#pragma unroll
    for (int i = 0; i < 4; i++)
#pragma unroll
      for (int r = 0; r < 4; r++)
        red2[wave & 1][wm + i * 16 + fq * 4 + r] = rsum[i][r];
  __syncthreads();
  float* ws = (path ? wsum_ep : wsum_es) + b * 128;
  if (t < 128) atomicAdd(&ws[t], red2[0][t] + red2[1][t]);
}

// ---------------------------------------------------------------------------
// Kernel 5: se/pe score, q-split. Grid 256, 512 thr.
// Block = (path, b, q-quarter of 32): C[32 q][512 k] fully in registers
// (acc[2][4] f32x4), K=256 BK=64 single-buffered, same swizzle as tile64.
// l[q] exact in-block (shfl + red LDS); wsum[k] += col-sums of e/l via
// atomicAdd (4 qq blocks per (path,b) collide). No Sc, no l bufs, no colsum2.
// ---------------------------------------------------------------------------
__global__ __launch_bounds__(512) void score_sepe(
    const ushort* __restrict__ Y, const ushort* __restrict__ sub_b,
    const ushort* __restrict__ prod_b, const float* __restrict__ iw,
    const float* __restrict__ t_se, const float* __restrict__ t_pe,
    float* __restrict__ wsum_se, float* __restrict__ wsum_pe)
{
  __shared__ __align__(16) ushort As[32 * 64];
  __shared__ __align__(16) ushort Bs[256 * 64];
  __shared__ float red[8][32];
  const int f = blockIdx.x, t = threadIdx.x;
  const int path = f >> 7, l = f & 127, b = l >> 2, qq = l & 3;
  const int wv = t >> 6, lane = t & 63;
  const int fl = lane & 15, fq = lane >> 4;
  const ushort* A  = (path ? prod_b : sub_b) + (size_t)b * 32768 + qq * 32 * 256;
  const ushort* Bt = Y + (size_t)b * 512 * 768 + 256 + path * 256;
  const float* Tq = (path ? t_pe : t_se) + b * 512;
  float* ws = (path ? wsum_pe : wsum_se) + b * 512;
  const size_t ib = (size_t)b * 65536 + (size_t)(qq * 32) * 512;

  f32x4 acc[2][4] = {};

  // GEMM: C[32 q][512 k], contraction K=256 (d_cpd), BK=64, n-halves of 256.
  for (int nh = 0; nh < 2; ++nh) {
    for (int k0 = 0; k0 < 256; k0 += 64) {
      __syncthreads();
      if (t < 256) {
        const int ar = t >> 3;
        gload16(A + (size_t)ar * 256 + k0 + 8 * ((t & 7) ^ (ar & 7)),
                As + ar * 64 + (t & 7) * 8);
      }
#pragma unroll
      for (int i = 0; i < 4; ++i) {
        const int br = i * 64 + (t >> 3);
        gload16(Bt + (size_t)(nh * 256 + br) * 768 + k0 + 8 * ((t & 7) ^ (br & 7)),
                Bs + br * 64 + (t & 7) * 8);
      }
      __syncthreads();
#pragma unroll
      for (int kk = 0; kk < 2; ++kk) {
        bf16x8 af[2], bfr[2];
#pragma unroll
        for (int m = 0; m < 2; ++m) {
          const int row = m * 16 + fl;
          af[m] = *(const bf16x8*)(As + row * 64 + 8 * (((kk << 2) + fq) ^ (row & 7)));
        }
#pragma unroll
        for (int n = 0; n < 2; ++n) {
          const int row = wv * 32 + n * 16 + fl;
          bfr[n] = *(const bf16x8*)(Bs + row * 64 + 8 * (((kk << 2) + fq) ^ (row & 7)));
        }
#pragma unroll
        for (int m = 0; m < 2; ++m)
#pragma unroll
          for (int n = 0; n < 2; ++n)
            acc[m][nh * 2 + n] = __builtin_amdgcn_mfma_f32_16x16x32_bf16(
                af[m], bfr[n], acc[m][nh * 2 + n], 0, 0, 0);
      }
    }
  }

  // bias + iw + exp
  float tv[4];
  int colv[4];
#pragma unroll
  for (int c = 0; c < 4; ++c) {
    const int nh = c >> 1, n = c & 1;
    colv[c] = nh * 256 + wv * 32 + n * 16 + fl;
    tv[c] = Tq[colv[c]];
  }
  float rsum[2][4];
#pragma unroll
  for (int m = 0; m < 2; ++m)
#pragma unroll
    for (int r = 0; r < 4; ++r) rsum[m][r] = 0.f;
#pragma unroll
  for (int m = 0; m < 2; ++m)
#pragma unroll
    for (int c = 0; c < 4; ++c)
#pragma unroll
      for (int r = 0; r < 4; ++r) {
        const int row = m * 16 + fq * 4 + r;      // local q in [0,32)
        float s = acc[m][c][r] * SCALE_INV + tv[c];
        if (path == 0) s += iw[ib + (size_t)row * 512 + colv[c]];
        const float e = __expf(s);
        acc[m][c][r] = e;
        rsum[m][r] += e;
      }
  // l[q]: row sums. shfl over fl bits (same fq -> same row), then cross-wave.
#pragma unroll
  for (int mm = 1; mm <= 8; mm <<= 1)
#pragma unroll
    for (int m = 0; m < 2; ++m)
#pragma unroll
      for (int r = 0; r < 4; ++r)
        rsum[m][r] += __shfl_xor(rsum[m][r], mm);
  if (fl == 0)
#pragma unroll
    for (int m = 0; m < 2; ++m)
#pragma unroll
      for (int r = 0; r < 4; ++r)
        red[wv][m * 16 + fq * 4 + r] = rsum[m][r];
  __syncthreads();
  float invl[2][4];
#pragma unroll
  for (int m = 0; m < 2; ++m)
#pragma unroll
    for (int r = 0; r < 4; ++r) {
      const int row = m * 16 + fq * 4 + r;
      float lsum = 0.f;
#pragma unroll
      for (int w = 0; w < 8; ++w) lsum += red[w][row];
      invl[m][r] = 1.f / lsum;
    }
  // wsum[k] += column sums of e/l (32 q in-block; shfl over fq bits).
#pragma unroll
  for (int c = 0; c < 4; ++c) {
    float w = 0.f;
#pragma unroll
    for (int m = 0; m < 2; ++m)
#pragma unroll
      for (int r = 0; r < 4; ++r) w += acc[m][c][r] * invl[m][r];
    w += __shfl_xor(w, 16);
    w += __shfl_xor(w, 32);
    if (fq == 0) atomicAdd(&ws[colv[c]], w);
  }
}

// ---------------------------------------------------------------------------
// Kernel 6: wx = wsum @ X_kv (bf16 X). Grid 384.
// ---------------------------------------------------------------------------
__global__ __launch_bounds__(256) void wx_fused(
    const float* __restrict__ wsum_se, const float* __restrict__ wsum_pe,
    const float* __restrict__ wsum_es, const float* __restrict__ wsum_ep,
    const ushort* __restrict__ enz_b, const ushort* __restrict__ sub_b,
    const ushort* __restrict__ prod_b,
    float* __restrict__ wx_se, float* __restrict__ wx_pe,
    float* __restrict__ wx_es, float* __restrict__ wx_ep)
{
  __shared__ float wse[256], wpe[256];
  const int f = blockIdx.x, t = threadIdx.x;
  if (f < 320) {
    const int ch = f % 5, tmp = f / 5, b = tmp & 31, kh = tmp >> 5;
    wse[t] = wsum_se[b * 512 + kh * 256 + t];
    wpe[t] = wsum_pe[b * 512 + kh * 256 + t];
    __syncthreads();
    const int c = ch * 256 + t;
    const ushort* X = enz_b + (size_t)b * 512 * 1280 + (size_t)(kh * 256) * 1280 + c;
    float a_se = 0.f, a_pe = 0.f;
#pragma unroll 4
    for (int k = 0; k < 256; k++) {
      const float x = bf2f(X[(size_t)k * 1280]);
      a_se += wse[k] * x;
      a_pe += wpe[k] * x;
    }
    atomicAdd(&wx_se[b * 1280 + c], a_se);
    atomicAdd(&wx_pe[b * 1280 + c], a_pe);
  } else if (f < 352) {
    const int b = f - 320;
    const ushort* X = sub_b + (size_t)b * 128 * 256 + t;
    float a = 0.f;
#pragma unroll 4
    for (int k = 0; k < 128; k++) a += wsum_es[b * 128 + k] * bf2f(X[(size_t)k * 256]);
    wx_es[b * 256 + t] = a;
  } else {
    const int b = f - 352;
    const ushort* X = prod_b + (size_t)b * 128 * 256 + t;
    float a = 0.f;
#pragma unroll 4
    for (int k = 0; k < 128; k++) a += wsum_ep[b * 128 + k] * bf2f(X[(size_t)k * 256]);
    wx_ep[b * 256 + t] = a;
  }
}

// ---------------------------------------------------------------------------
// Kernel 7: out += inv * (wx chunk @ Wv chunk), c-split for occupancy.
// Grid 96. Bias pre-folded into out by prep.
// ---------------------------------------------------------------------------
__global__ __launch_bounds__(256) void out_gemv(
    const float* __restrict__ wx_es, const float* __restrict__ wx_se,
    const float* __restrict__ wx_ep, const float* __restrict__ wx_pe,
    const float* __restrict__ enz_Wv, const float* __restrict__ sub_Wv,
    const float* __restrict__ prod_Wv,
    float* __restrict__ out)
{
  __shared__ float sw[32][64];
  const int f = blockIdx.x, t = threadIdx.x;
  const float* wx; const float* Wv; int Cdim, qoff, nb, cc; float inv;
  if (f < 40)      { wx = wx_se; Wv = sub_Wv;  Cdim = 1280; inv = 1.f / 128.f; qoff = 512;  nb = f & 1;        cc = f >> 1; }
  else if (f < 80) { wx = wx_pe; Wv = prod_Wv; Cdim = 1280; inv = 1.f / 128.f; qoff = 1536; nb = (f - 40) & 1; cc = (f - 40) >> 1; }
  else if (f < 88) { wx = wx_es; Wv = enz_Wv;  Cdim = 256;  inv = 1.f / 512.f; qoff = 0;    nb = (f - 80) & 1; cc = (f - 80) >> 1; }
  else             { wx = wx_ep; Wv = enz_Wv;  Cdim = 256;  inv = 1.f / 512.f; qoff = 1024; nb = (f - 88) & 1; cc = (f - 88) >> 1; }
  const int c0 = cc * 64, n = nb * 256 + t;
#pragma unroll
  for (int i = 0; i < 8; i++) {
    const int idx = t + i * 256, b = idx >> 6, c = idx & 63;
    sw[b][c] = wx[(size_t)b * Cdim + c0 + c];
  }
  __syncthreads();
  float acc[32];
#pragma unroll
  for (int b = 0; b < 32; b++) acc[b] = 0.f;
  for (int c = 0; c < 64; c += 4) {
    const float w0 = Wv[(size_t)(c0 + c) * 512 + n];
    const float w1 = Wv[(size_t)(c0 + c + 1) * 512 + n];
    const float w2 = Wv[(size_t)(c0 + c + 2) * 512 + n];
    const float w3 = Wv[(size_t)(c0 + c + 3) * 512 + n];
#pragma unroll
    for (int b = 0; b < 32; b++) {
      const float4 s = *(const float4*)&sw[b][c];
      acc[b] += s.x * w0 + s.y * w1 + s.z * w2 + s.w * w3;
    }
  }
#pragma unroll
  for (int b = 0; b < 32; b++)
    atomicAdd(&out[(size_t)b * 2048 + qoff + n], acc[b] * inv);
}

// ---------------------------------------------------------------------------
extern "C" void kernel_launch(void* const* d_in, const int* in_sizes, int n_in,
                              void* d_out, int out_size, void* d_ws, size_t ws_size,
                              hipStream_t stream)
{
  (void)in_sizes; (void)n_in; (void)out_size; (void)ws_size;
  const float* enz     = (const float*)d_in[0];   // [32,512,1280]
  const float* sub     = (const float*)d_in[1];   // [32,128,256]
  const float* prod    = (const float*)d_in[2];   // [32,128,256]
  const float* iw      = (const float*)d_in[6];   // [32,128,512]
  const float* enz_Wq  = (const float*)d_in[7];
  const float* enz_bq  = (const float*)d_in[8];
  const float* enz_Wk  = (const float*)d_in[9];
  const float* enz_Wv  = (const float*)d_in[11];
  const float* enz_bv  = (const float*)d_in[12];
  const float* sub_Wq  = (const float*)d_in[13];
  const float* sub_bq  = (const float*)d_in[14];
  const float* sub_Wk  = (const float*)d_in[15];
  const float* sub_Wv  = (const float*)d_in[17];
  const float* sub_bv  = (const float*)d_in[18];
  const float* prod_Wq = (const float*)d_in[19];
  const float* prod_bq = (const float*)d_in[20];
  const float* prod_Wk = (const float*)d_in[21];
  const float* prod_Wv = (const float*)d_in[23];
  const float* prod_bv = (const float*)d_in[24];
  float* out = (float*)d_out;

  char* wsb = (char*)d_ws;
  size_t off = 0;
  auto alloc = [&](size_t bytes) {
    void* p = wsb + off;
    off += (bytes + 255) & ~(size_t)255;
    return p;
  };
  ushort* enz_b   = (ushort*)alloc((size_t)32 * 512 * 1280 * 2);
  ushort* sub_b   = (ushort*)alloc((size_t)32 * 128 * 256 * 2);
  ushort* prod_b  = (ushort*)alloc((size_t)32 * 128 * 256 * 2);
  ushort* eWq_b   = (ushort*)alloc((size_t)1280 * 512 * 2);
  ushort* sWk_b   = (ushort*)alloc((size_t)1280 * 512 * 2);
  ushort* pWk_b   = (ushort*)alloc((size_t)1280 * 512 * 2);
  ushort* eWk_b   = (ushort*)alloc((size_t)256 * 512 * 2);
  ushort* sWq_b   = (ushort*)alloc((size_t)256 * 512 * 2);
  ushort* pWq_b   = (ushort*)alloc((size_t)256 * 512 * 2);
  ushort* W3t     = (ushort*)alloc((size_t)768 * 1280 * 2);
  ushort* Y       = (ushort*)alloc((size_t)16384 * 768 * 2);
  float*  u_s_s   = (float*)alloc(1280 * 4);
  float*  u_p_s   = (float*)alloc(1280 * 4);
  float*  u_e_s   = (float*)alloc(256 * 4);
  float*  t_es    = (float*)alloc(4096 * 4);
  float*  t_ep    = (float*)alloc(4096 * 4);
  float*  t_se    = (float*)alloc(16384 * 4);
  float*  t_pe    = (float*)alloc(16384 * 4);
  // zero region (contiguous, 122880 floats = 480 blocks of 256):
  float* wsum_es = (float*)alloc(4096 * 4);
  float* wsum_ep = (float*)alloc(4096 * 4);
  float* wsum_se = (float*)alloc(16384 * 4);
  float* wsum_pe = (float*)alloc(16384 * 4);
  float* wx_se   = (float*)alloc(40960 * 4);
  float* wx_pe   = (float*)alloc(40960 * 4);
  // non-zeroed (plain stores):
  float* wx_es   = (float*)alloc(8192 * 4);
  float* wx_ep   = (float*)alloc(8192 * 4);

  static bool ygemm_attr_set = false;
  if (!ygemm_attr_set) {
    hipFuncSetAttribute(reinterpret_cast<const void*>(y_gemm),
                        hipFuncAttributeMaxDynamicSharedMemorySize, 81920);
    ygemm_attr_set = true;
  }

  const dim3 blk(256);

  prep_fused<<<13328, blk, 0, stream>>>(
      enz, sub, prod, enz_b, sub_b, prod_b,
      enz_Wq, enz_Wk, sub_Wq, sub_Wk, prod_Wq, prod_Wk,
      eWq_b, eWk_b, sWq_b, sWk_b, pWq_b, pWk_b,
      enz_bq, sub_bq, prod_bq, enz_bv, sub_bv, prod_bv,
      u_s_s, u_p_s, u_e_s, wsum_es, out);

  fold_w3<<<332, blk, 0, stream>>>(
      eWq_b, eWk_b, sWq_b, sWk_b, pWq_b, pWk_b,
      sub_b, prod_b, enz_b, u_e_s, u_s_s, u_p_s,
      W3t, t_es, t_ep, t_se, t_pe);

  y_gemm<<<512, 512, 81920, stream>>>(enz_b, W3t, Y);

  score_esep<<<256, blk, 0, stream>>>(
      Y, sub_b, prod_b, iw, t_es, t_ep, wsum_es, wsum_ep);

  score_sepe<<<256, 512, 0, stream>>>(
      Y, sub_b, prod_b, iw, t_se, t_pe, wsum_se, wsum_pe);

  wx_fused<<<384, blk, 0, stream>>>(
      wsum_se, wsum_pe, wsum_es, wsum_ep, enz_b, sub_b, prod_b,
      wx_se, wx_pe, wx_es, wx_ep);

  out_gemv<<<96, blk, 0, stream>>>(
      wx_es, wx_se, wx_ep, wx_pe, enz_Wv, sub_Wv, prod_Wv, out);
}

// Round 10
// 313.161 us; speedup vs baseline: 1.0742x; 1.0742x over previous
//
#include <hip/hip_runtime.h>
#include <cstdint>
#include <cstddef>

// ---------------------------------------------------------------------------
// EnzymeCompoundCrossAttention — R12 = revert to R8 (best measured: 313.4 µs;
// R11's Sc-elimination regressed to 336 via 4x Y re-reads + single-buffered
// drains). Exact-N y_gemm (BN=192, grid 256 full density), bias cols outside
// the GEMM, BK=32 score path + colsum2.
//
// Algebra (R1/R2/R4 verified):
//   score = x_q (Wq Wk^T) x_k^T / S + (x_k . (Wk bq)) / S   (+iw bias; bk and
//   q-constant terms cancel in softmax).
//   All big GEMMs collapse into Y = enz @ W3 with W3t [768 x 1280]:
//   rows [0,256)=M_big^T, [256,512)=M_se, [512,768)=M_pe.  Y [16384 x 768].
//   Bias terms: t_se/t_pe[row] = dot(enz[row,:], u_{s,p}) * S^-1 (fold_w3);
//   t_es/t_ep[b,k] = dot(x_k, u_e) * S^-1 (fold_w3).
//   Score GEMMs contract over d_cpd=256.
//   out_quarter = (1/Lq) * (wsum @ X_kv) @ Wv + bv.
// Launches: prep -> fold -> y_gemm -> score -> colsum2 -> wx -> out (7).
// ---------------------------------------------------------------------------

#define SCALE_INV 0.044194173824159216f  // 1/sqrt(512)

typedef short bf16x8 __attribute__((ext_vector_type(8)));
typedef float f32x4  __attribute__((ext_vector_type(4)));

__device__ __forceinline__ ushort f2bf(float f) {
  union { float f; unsigned u; } c; c.f = f;
  unsigned u = c.u + 0x7fffu + ((c.u >> 16) & 1u);
  return (ushort)(u >> 16);
}
__device__ __forceinline__ float bf2f(ushort h) {
  return __uint_as_float(((unsigned)h) << 16);
}
__device__ __forceinline__ void gload16(const ushort* g, ushort* l) {
  __builtin_amdgcn_global_load_lds(
      (const __attribute__((address_space(1))) void*)g,
      (__attribute__((address_space(3))) void*)l, 16, 0, 0);
}

// ---------------------------------------------------------------------------
// Kernel 1: prep — segmented flat grid. Grid 13424.
//   [0,10240)      cvt enz f32->bf16
//   [10240,10752)  cvt sub
//   [10752,11264)  cvt prod
//   [11264,12416)  cvt 6 weight mats to bf16
//   [12416,12592)  u vectors -> f32 scaled: u_s_s[1280], u_p_s[1280], u_e_s[256]
//   [12592,13168)  zero 147456 floats (wsum/l/wx region)
//   [13168,13424)  out init = bias
// ---------------------------------------------------------------------------
__device__ __forceinline__ void cvt8(const float* __restrict__ in,
                                     ushort* __restrict__ out, int blk, int n) {
  int i = (blk * 256 + (int)threadIdx.x) * 8;
  if (i >= n) return;
  float4 a = *(const float4*)(in + i);
  float4 b = *(const float4*)(in + i + 4);
  ushort o[8] = { f2bf(a.x), f2bf(a.y), f2bf(a.z), f2bf(a.w),
                  f2bf(b.x), f2bf(b.y), f2bf(b.z), f2bf(b.w) };
  *(uint4*)(out + i) = *(uint4*)o;
}

__global__ __launch_bounds__(256) void prep_fused(
    const float* __restrict__ enz, const float* __restrict__ sub,
    const float* __restrict__ prod,
    ushort* __restrict__ enz_b, ushort* __restrict__ sub_b, ushort* __restrict__ prod_b,
    const float* __restrict__ enz_Wq, const float* __restrict__ enz_Wk,
    const float* __restrict__ sub_Wq, const float* __restrict__ sub_Wk,
    const float* __restrict__ prod_Wq, const float* __restrict__ prod_Wk,
    ushort* __restrict__ eWq_b, ushort* __restrict__ eWk_b,
    ushort* __restrict__ sWq_b, ushort* __restrict__ sWk_b,
    ushort* __restrict__ pWq_b, ushort* __restrict__ pWk_b,
    const float* __restrict__ enz_bq, const float* __restrict__ sub_bq,
    const float* __restrict__ prod_bq,
    const float* __restrict__ enz_bv, const float* __restrict__ sub_bv,
    const float* __restrict__ prod_bv,
    float* __restrict__ u_s_s, float* __restrict__ u_p_s,
    float* __restrict__ u_e_s,
    float* __restrict__ zero_base, float* __restrict__ out)
{
  const int f = blockIdx.x, t = threadIdx.x;
  if (f < 10240) { cvt8(enz, enz_b, f, 20971520); return; }
  if (f < 10752) { cvt8(sub, sub_b, f - 10240, 1048576); return; }
  if (f < 11264) { cvt8(prod, prod_b, f - 10752, 1048576); return; }
  if (f < 12416) {
    const int l = f - 11264;
    if (l < 320)       cvt8(enz_Wq,  eWq_b, l,        655360);
    else if (l < 640)  cvt8(sub_Wk,  sWk_b, l - 320,  655360);
    else if (l < 960)  cvt8(prod_Wk, pWk_b, l - 640,  655360);
    else if (l < 1024) cvt8(enz_Wk,  eWk_b, l - 960,  131072);
    else if (l < 1088) cvt8(sub_Wq,  sWq_b, l - 1024, 131072);
    else               cvt8(prod_Wq, pWq_b, l - 1088, 131072);
    return;
  }
  if (f < 12592) {
    // u[d] = dot(Wk[d,:512], bq) * SCALE_INV. 16 rows/block, 16 threads/row.
    const int g = f - 12416;
    const float* W; const float* bv; float* U; int d0;
    if (g < 80)       { W = sub_Wk;  bv = sub_bq;  U = u_s_s; d0 = g * 16; }
    else if (g < 160) { W = prod_Wk; bv = prod_bq; U = u_p_s; d0 = (g - 80) * 16; }
    else              { W = enz_Wk;  bv = enz_bq;  U = u_e_s; d0 = (g - 160) * 16; }
    const int r = t >> 4, i = t & 15, d = d0 + r;
    const float* row = W + (size_t)d * 512;
    float s = 0.f;
#pragma unroll
    for (int j = 0; j < 32; j++) s += row[i + j * 16] * bv[i + j * 16];
    s += __shfl_xor(s, 1); s += __shfl_xor(s, 2);
    s += __shfl_xor(s, 4); s += __shfl_xor(s, 8);
    if (i == 0) U[d] = s * SCALE_INV;
    return;
  }
  if (f < 13168) { zero_base[(f - 12592) * 256 + t] = 0.f; return; }
  {
    const int idx = (f - 13168) * 256 + t;  // < 65536 = 32*2048
    const int col = idx & 2047;
    const int q = col >> 9, n = col & 511;
    const float* bvp = (q == 1) ? sub_bv : (q == 3) ? prod_bv : enz_bv;
    out[idx] = bvp[n];
  }
}

// ---------------------------------------------------------------------------
// MFMA tile core (128x128, 2-barrier, used by fold_w3 / score_fused).
// ---------------------------------------------------------------------------
__device__ __forceinline__ void mfma_tile(
    const ushort* __restrict__ A, int lda,
    const ushort* __restrict__ Bt, int ldb, int K,
    int bm, int bn, ushort* AsBase, ushort* BsBase, f32x4 (&acc)[4][4])
{
  const int t = threadIdx.x, wave = t >> 6, lane = t & 63;
  const int srow = wave * 16 + (lane >> 2);
  const int sseg = (lane & 3) * 8;
  const ushort* Ag0 = A + (size_t)(bm + srow) * lda + sseg;
  const ushort* Ag1 = Ag0 + (size_t)64 * lda;
  const ushort* Bg0 = Bt + (size_t)(bn + srow) * ldb + sseg;
  const ushort* Bg1 = Bg0 + (size_t)64 * ldb;
  ushort* AsP0 = AsBase + srow * 32 + sseg;
  ushort* AsP1 = AsP0 + 64 * 32;
  ushort* BsP0 = BsBase + srow * 32 + sseg;
  ushort* BsP1 = BsP0 + 64 * 32;
  const int wm = (wave >> 1) * 64, wn = (wave & 1) * 64;
  const int fl = lane & 15, fq = lane >> 4;
  const bf16x8* ArP = (const bf16x8*)(AsBase + (wm + fl) * 32 + fq * 8);
  const bf16x8* BrP = (const bf16x8*)(BsBase + (wn + fl) * 32 + fq * 8);
  for (int k0 = 0; k0 < K; k0 += 32) {
    __syncthreads();
    gload16(Ag0 + k0, AsP0);
    gload16(Ag1 + k0, AsP1);
    gload16(Bg0 + k0, BsP0);
    gload16(Bg1 + k0, BsP1);
    __syncthreads();
    bf16x8 af[4], bfr[4];
#pragma unroll
    for (int i = 0; i < 4; i++) af[i] = ArP[i * 64];
#pragma unroll
    for (int j = 0; j < 4; j++) bfr[j] = BrP[j * 64];
#pragma unroll
    for (int i = 0; i < 4; i++)
#pragma unroll
      for (int j = 0; j < 4; j++)
        acc[i][j] = __builtin_amdgcn_mfma_f32_16x16x32_bf16(af[i], bfr[j], acc[i][j], 0, 0, 0);
  }
}

// ---------------------------------------------------------------------------
// Kernel 2: fold — grid 140.
//   [0,60):   W3t rows 0..767 via 3 MFMA GEMMs, K=512.
//   [60,76):  t_es/t_ep[b*128+k] = dot(X[k,:], u_e_s) (u pre-scaled).
//   [76,140): t_se/t_pe[row] = dot(enz_b[row,:], u_{s,p}_s). 256 rows/block,
//             16 lanes/row coalesced.
// ---------------------------------------------------------------------------
__global__ __launch_bounds__(256) void fold_w3(
    const ushort* __restrict__ eWq_b, const ushort* __restrict__ eWk_b,
    const ushort* __restrict__ sWq_b, const ushort* __restrict__ sWk_b,
    const ushort* __restrict__ pWq_b, const ushort* __restrict__ pWk_b,
    const ushort* __restrict__ sub_b, const ushort* __restrict__ prod_b,
    const ushort* __restrict__ enz_b,
    const float* __restrict__ u_e_s, const float* __restrict__ u_s_s,
    const float* __restrict__ u_p_s,
    ushort* __restrict__ W3t, float* __restrict__ t_es, float* __restrict__ t_ep,
    float* __restrict__ t_se, float* __restrict__ t_pe)
{
  __shared__ __align__(16) ushort As[128 * 32];
  __shared__ __align__(16) ushort Bs[128 * 32];
  __shared__ float us[256];
  __shared__ float us2[2][1280];
  const int f = blockIdx.x, t = threadIdx.x;
  if (f >= 76) {
    const int g2 = f - 76;          // [0,64)
    for (int i = t; i < 1280; i += 256) { us2[0][i] = u_s_s[i]; us2[1][i] = u_p_s[i]; }
    __syncthreads();
    const int lane16 = t & 15, rg = t >> 4;
    for (int p = 0; p < 16; ++p) {
      const int row = g2 * 256 + p * 16 + rg;
      const ushort* xr = enz_b + (size_t)row * 1280;
      float ss = 0.f, sp = 0.f;
#pragma unroll
      for (int q = 0; q < 10; ++q) {
        const int c0 = q * 128 + lane16 * 8;
        bf16x8 v = *(const bf16x8*)(xr + c0);
#pragma unroll
        for (int i = 0; i < 8; ++i) {
          const float x = bf2f((ushort)v[i]);
          ss += x * us2[0][c0 + i];
          sp += x * us2[1][c0 + i];
        }
      }
      ss += __shfl_xor(ss, 1); ss += __shfl_xor(ss, 2);
      ss += __shfl_xor(ss, 4); ss += __shfl_xor(ss, 8);
      sp += __shfl_xor(sp, 1); sp += __shfl_xor(sp, 2);
      sp += __shfl_xor(sp, 4); sp += __shfl_xor(sp, 8);
      if (lane16 == 0) { t_se[row] = ss; t_pe[row] = sp; }
    }
    return;
  }
  if (f >= 60) {
    const int g = f - 60, path = g >> 3, blk8 = g & 7;
    const ushort* Xb = path ? prod_b : sub_b;
    float* T = path ? t_ep : t_es;
    us[t] = u_e_s[t];
    __syncthreads();
#pragma unroll
    for (int e = 0; e < 2; ++e) {
      const int row = blk8 * 512 + e * 256 + t;   // (b*128+k) flat, < 4096
      const ushort* xr = Xb + (size_t)row * 256;
      float s = 0.f;
      for (int c = 0; c < 256; c += 8) {
        bf16x8 v = *(const bf16x8*)(xr + c);
#pragma unroll
        for (int i = 0; i < 8; ++i) s += bf2f((ushort)v[i]) * us[c + i];
      }
      T[row] = s;
    }
    return;
  }
  const int seg = f / 20, l = f % 20;
  const int bm = (l / 10) * 128, bn = (l % 10) * 128;
  const ushort* A  = (seg == 0) ? eWk_b : (seg == 1) ? sWq_b : pWq_b;
  const ushort* Bt = (seg == 0) ? eWq_b : (seg == 1) ? sWk_b : pWk_b;
  f32x4 acc[4][4] = {};
  mfma_tile(A, 512, Bt, 512, 512, bm, bn, As, Bs, acc);
  const int lane = t & 63, wave = t >> 6;
  const int wm = (wave >> 1) * 64, wn = (wave & 1) * 64;
  const int fl = lane & 15, fq = lane >> 4;
#pragma unroll
  for (int i = 0; i < 4; i++)
#pragma unroll
    for (int j = 0; j < 4; j++) {
      const int col = bn + wn + j * 16 + fl;
#pragma unroll
      for (int r = 0; r < 4; r++) {
        const int row = seg * 256 + bm + wm + i * 16 + fq * 4 + r;
        W3t[(size_t)row * 1280 + col] = f2bf(acc[i][j][r]);
      }
    }
}

// ---------------------------------------------------------------------------
// Kernel 3: Y = enz @ W3  (M=16384, N=768 exact, K=1280).
// BM=256 BN=192 BK=64, 8 waves (2M x 4N, 3 n-frags/wave), dbuf 112 KiB LDS.
// T2 both-sides swizzle; counted vmcnt(4); setprio; kk-outer MFMA.
// Grid 256 = 64 mt x 4 nt, 1 block/CU, XCD swizzle.
// Stage unit = 64 rows (1 gload16/thread): A=4 units, B=3 units per K-tile.
// ---------------------------------------------------------------------------
__device__ __forceinline__ void yg_stage_unit(
    const ushort* __restrict__ gbase, int k0, int u,
    ushort* ldsTile, int wv, int l, int srow8, int scol)
{
  const int row0 = u * 64 + wv * 8 + srow8;
  gload16(gbase + (size_t)row0 * 1280 + k0 + scol,
          ldsTile + u * 4096 + wv * 512 + l * 8);
}

__device__ __forceinline__ bf16x8 yg_frag(const ushort* tile, int row, int kk, int fq) {
  const int X = (kk * 64 + fq * 16) ^ ((row & 7) << 4);
  return *(const bf16x8*)((const char*)tile + row * 128 + X);
}

__global__ __launch_bounds__(512, 2) void y_gemm(
    const ushort* __restrict__ A,      // enz_b [16384][1280]
    const ushort* __restrict__ B,      // W3t   [768][1280]
    ushort* __restrict__ Y)            // [16384][768]
{
  extern __shared__ __align__(16) ushort lds[];
  const int t = threadIdx.x;
  const int wv = t >> 6, l = t & 63;
  const int fl = l & 15, fq = l >> 4;
  const int f = blockIdx.x;
  const int xcd = f & 7, slot = f >> 3;
  const int mt = xcd * 8 + (slot >> 2), nt = slot & 3;
  const int bm = mt * 256, bn = nt * 192;
  const int wm = (wv >> 2) * 128, wn = (wv & 3) * 48;
  const int srow8 = l >> 3;
  const int scol = 8 * ((l & 7) ^ srow8);     // inverse-swizzled source col
  const ushort* Ag = A + (size_t)bm * 1280;
  const ushort* Bg = B + (size_t)bn * 1280;

  ushort* A0 = lds;              // 16384 elems (256x64)
  ushort* B0 = lds + 16384;      // 12288 elems (192x64)
  ushort* A1 = lds + 28672;
  ushort* B1 = lds + 45056;

  f32x4 acc[8][3] = {};

  // ---- prologue: tile0 fully + tile1 A ----
#pragma unroll
  for (int u = 0; u < 4; ++u) yg_stage_unit(Ag, 0, u, A0, wv, l, srow8, scol);
#pragma unroll
  for (int u = 0; u < 3; ++u) yg_stage_unit(Bg, 0, u, B0, wv, l, srow8, scol);
#pragma unroll
  for (int u = 0; u < 4; ++u) yg_stage_unit(Ag, 64, u, A1, wv, l, srow8, scol);
  asm volatile("s_waitcnt vmcnt(4)" ::: "memory");
  __builtin_amdgcn_s_barrier();
  __builtin_amdgcn_sched_barrier(0);

  for (int j = 0; j < 20; ++j) {
    const int p = j & 1;
    const ushort* At = p ? A1 : A0;
    const ushort* Bt = p ? B1 : B0;
    ushort* Bo = p ? B0 : B1;
    const int kn = (j + 1) * 64;

    bf16x8 bf_[3][2];
#pragma unroll
    for (int n = 0; n < 3; ++n)
#pragma unroll
      for (int kk = 0; kk < 2; ++kk)
        bf_[n][kk] = yg_frag(Bt, wn + n * 16 + fl, kk, fq);

#pragma unroll
    for (int mp = 0; mp < 4; ++mp) {
      if (mp < 3 && j < 19) yg_stage_unit(Bg, kn, mp, Bo, wv, l, srow8, scol);
      bf16x8 a0[2], a1v[2];
#pragma unroll
      for (int kk = 0; kk < 2; ++kk) {
        a0[kk]  = yg_frag(At, wm + (mp * 2) * 16 + fl, kk, fq);
        a1v[kk] = yg_frag(At, wm + (mp * 2 + 1) * 16 + fl, kk, fq);
      }
      __builtin_amdgcn_s_setprio(1);
#pragma unroll
      for (int kk = 0; kk < 2; ++kk)
#pragma unroll
        for (int n = 0; n < 3; ++n) {
          acc[mp * 2][n] = __builtin_amdgcn_mfma_f32_16x16x32_bf16(
              a0[kk], bf_[n][kk], acc[mp * 2][n], 0, 0, 0);
          acc[mp * 2 + 1][n] = __builtin_amdgcn_mfma_f32_16x16x32_bf16(
              a1v[kk], bf_[n][kk], acc[mp * 2 + 1][n], 0, 0, 0);
        }
      __builtin_amdgcn_s_setprio(0);
    }

    // ---- boundary: release buf, stage A(j+2) into it, counted wait ----
    asm volatile("" ::: "memory");
    __builtin_amdgcn_s_barrier();
    if (j + 2 < 20) {
      ushort* Ao = (ushort*)At;
#pragma unroll
      for (int u = 0; u < 4; ++u)
        yg_stage_unit(Ag, (j + 2) * 64, u, Ao, wv, l, srow8, scol);
    }
    if (j < 18) asm volatile("s_waitcnt vmcnt(4)" ::: "memory");
    else        asm volatile("s_waitcnt vmcnt(0)" ::: "memory");
    __builtin_amdgcn_s_barrier();
    __builtin_amdgcn_sched_barrier(0);
  }

  // ---- epilogue: C-write ----
#pragma unroll
  for (int m = 0; m < 8; ++m)
#pragma unroll
    for (int n = 0; n < 3; ++n)
#pragma unroll
      for (int r = 0; r < 4; ++r) {
        const int row = bm + wm + m * 16 + fq * 4 + r;
        const int col = bn + wn + n * 16 + fl;
        Y[(size_t)row * 768 + col] = f2bf(acc[m][n][r]);
      }
}

// ---------------------------------------------------------------------------
// Kernel 4: all 4 score GEMMs + softmax plumbing. Grid 512. K=256.
// Y stride 768; t_es/t_ep/t_se/t_pe precomputed (pre-scaled).
// ---------------------------------------------------------------------------
__global__ __launch_bounds__(256) void score_fused(
    const ushort* __restrict__ Y, const ushort* __restrict__ sub_b,
    const ushort* __restrict__ prod_b, const float* __restrict__ iw,
    const float* __restrict__ t_es, const float* __restrict__ t_ep,
    const float* __restrict__ t_se, const float* __restrict__ t_pe,
    float* __restrict__ Sc_se, float* __restrict__ Sc_pe,
    float* __restrict__ l_se, float* __restrict__ l_pe,
    float* __restrict__ wsum_es, float* __restrict__ wsum_ep)
{
  __shared__ __align__(16) ushort As[128 * 32];
  __shared__ __align__(16) ushort Bs[128 * 32];
  __shared__ float red[2][128];
  __shared__ float red2[2][128];
  const int f = blockIdx.x, t = threadIdx.x;
  const int lane = t & 63, wave = t >> 6;
  const int wm = (wave >> 1) * 64, wn = (wave & 1) * 64;
  const int fl = lane & 15, fq = lane >> 4;
  f32x4 acc[4][4] = {};

  if (f < 256) {
    // ---- es / ep ----
    const int path = f >> 7, l = f & 127, b = l & 31, mt = l >> 5;
    const int bm = mt * 128;
    const ushort* X = (path ? prod_b : sub_b) + (size_t)b * 32768;
    mfma_tile(Y + (size_t)b * 512 * 768, 768, X, 256, 256, bm, 0, As, Bs, acc);
    const size_t ib = (size_t)b * 65536;
    const float* Tp = (path ? t_ep : t_es) + b * 128;
    float tvv[4];
#pragma unroll
    for (int j = 0; j < 4; j++) tvv[j] = Tp[wn + j * 16 + fl];
    float rsum[4][4];
#pragma unroll
    for (int i = 0; i < 4; i++)
#pragma unroll
      for (int r = 0; r < 4; r++) rsum[i][r] = 0.f;
#pragma unroll
    for (int i = 0; i < 4; i++)
#pragma unroll
      for (int j = 0; j < 4; j++)
#pragma unroll
        for (int r = 0; r < 4; r++) {
          const int row = wm + i * 16 + fq * 4 + r;   // local q
          const int col = wn + j * 16 + fl;           // k (global, bn=0)
          float s = acc[i][j][r] * SCALE_INV + tvv[j];
          if (path == 0) s += iw[ib + (size_t)col * 512 + (bm + row)];
          const float e = __expf(s);
          acc[i][j][r] = e;
          rsum[i][r] += e;
        }
#pragma unroll
    for (int m = 1; m <= 8; m <<= 1)
#pragma unroll
      for (int i = 0; i < 4; i++)
#pragma unroll
        for (int r = 0; r < 4; r++)
          rsum[i][r] += __shfl_xor(rsum[i][r], m);
    if (fl == 0)
#pragma unroll
      for (int i = 0; i < 4; i++)
#pragma unroll
        for (int r = 0; r < 4; r++)
          red[wave & 1][wm + i * 16 + fq * 4 + r] = rsum[i][r];
    __syncthreads();
    float csum[4] = { 0.f, 0.f, 0.f, 0.f };
#pragma unroll
    for (int i = 0; i < 4; i++)
#pragma unroll
      for (int r = 0; r < 4; r++) {
        const int row = wm + i * 16 + fq * 4 + r;
        const float invr = 1.f / (red[0][row] + red[1][row]);
#pragma unroll
        for (int j = 0; j < 4; j++) csum[j] += acc[i][j][r] * invr;
      }
#pragma unroll
    for (int m = 16; m <= 32; m <<= 1)
#pragma unroll
      for (int j = 0; j < 4; j++) csum[j] += __shfl_xor(csum[j], m);
    if (fq == 0)
#pragma unroll
      for (int j = 0; j < 4; j++) red2[wave >> 1][wn + j * 16 + fl] = csum[j];
    __syncthreads();
    float* ws = (path ? wsum_ep : wsum_es) + b * 128;
    if (t < 128) atomicAdd(&ws[t], red2[0][t] + red2[1][t]);
  } else {
    // ---- se / pe ----
    const int g = f - 256, path = g >> 7, l = g & 127, b = l & 31, nt = l >> 5;
    const int bn = nt * 128;
    const ushort* A  = (path ? prod_b : sub_b) + (size_t)b * 32768;
    const ushort* Bt = Y + (size_t)b * 512 * 768 + 256 + path * 256;
    mfma_tile(A, 256, Bt, 768, 256, 0, bn, As, Bs, acc);
    const size_t ib = (size_t)b * 65536;
    float* Sc = (path ? Sc_pe : Sc_se) + ib;
    const float* Tq = (path ? t_pe : t_se) + b * 512;
    float tv[4];
#pragma unroll
    for (int j = 0; j < 4; j++) tv[j] = Tq[bn + wn + j * 16 + fl];
    float rsum[4][4];
#pragma unroll
    for (int i = 0; i < 4; i++)
#pragma unroll
      for (int r = 0; r < 4; r++) rsum[i][r] = 0.f;
#pragma unroll
    for (int i = 0; i < 4; i++)
#pragma unroll
      for (int j = 0; j < 4; j++)
#pragma unroll
        for (int r = 0; r < 4; r++) {
          const int row = wm + i * 16 + fq * 4 + r;   // q (global, bm=0)
          const int col = wn + j * 16 + fl;           // local k
          float s = acc[i][j][r] * SCALE_INV + tv[j];
          if (path == 0) s += iw[ib + (size_t)row * 512 + (bn + col)];
          const float e = __expf(s);
          Sc[(size_t)row * 512 + bn + col] = e;
          rsum[i][r] += e;
        }
#pragma unroll
    for (int m = 1; m <= 8; m <<= 1)
#pragma unroll
      for (int i = 0; i < 4; i++)
#pragma unroll
        for (int r = 0; r < 4; r++)
          rsum[i][r] += __shfl_xor(rsum[i][r], m);
    if (fl == 0)
#pragma unroll
      for (int i = 0; i < 4; i++)
#pragma unroll
        for (int r = 0; r < 4; r++)
          red[wave & 1][wm + i * 16 + fq * 4 + r] = rsum[i][r];
    __syncthreads();
    float* lr = (path ? l_pe : l_se) + b * 128;
    if (t < 128) atomicAdd(&lr[t], red[0][t] + red[1][t]);
  }
}

// ---------------------------------------------------------------------------
// Kernel 5: finish se/pe colsum: wsum[b,k] += sum_q Sc[b,q,k] / l[b,q].
// ---------------------------------------------------------------------------
__global__ __launch_bounds__(256) void colsum2(
    const float* __restrict__ Sc_se, const float* __restrict__ Sc_pe,
    const float* __restrict__ l_se, const float* __restrict__ l_pe,
    float* __restrict__ wsum_se, float* __restrict__ wsum_pe)
{
  __shared__ float inv[32];
  const int f = blockIdx.x, t = threadIdx.x;
  const int path = f >> 7, l = f & 127, b = l & 31, qc = l >> 5;
  const float* Sc = (path ? Sc_pe : Sc_se) + (size_t)b * 65536 + (size_t)(qc * 32) * 512;
  const float* lv = (path ? l_pe : l_se) + b * 128 + qc * 32;
  float* ws = (path ? wsum_pe : wsum_se) + b * 512;
  if (t < 32) inv[t] = 1.f / lv[t];
  __syncthreads();
  float a0 = 0.f, a1 = 0.f;
  for (int q = 0; q < 32; q++) {
    const float iq = inv[q];
    a0 += Sc[(size_t)q * 512 + t] * iq;
    a1 += Sc[(size_t)q * 512 + 256 + t] * iq;
  }
  atomicAdd(&ws[t], a0);
  atomicAdd(&ws[t + 256], a1);
}

// ---------------------------------------------------------------------------
// Kernel 6: wx = wsum @ X_kv (bf16 X). Grid 384.
// ---------------------------------------------------------------------------
__global__ __launch_bounds__(256) void wx_fused(
    const float* __restrict__ wsum_se, const float* __restrict__ wsum_pe,
    const float* __restrict__ wsum_es, const float* __restrict__ wsum_ep,
    const ushort* __restrict__ enz_b, const ushort* __restrict__ sub_b,
    const ushort* __restrict__ prod_b,
    float* __restrict__ wx_se, float* __restrict__ wx_pe,
    float* __restrict__ wx_es, float* __restrict__ wx_ep)
{
  __shared__ float wse[256], wpe[256];
  const int f = blockIdx.x, t = threadIdx.x;
  if (f < 320) {
    const int ch = f % 5, tmp = f / 5, b = tmp & 31, kh = tmp >> 5;
    wse[t] = wsum_se[b * 512 + kh * 256 + t];
    wpe[t] = wsum_pe[b * 512 + kh * 256 + t];
    __syncthreads();
    const int c = ch * 256 + t;
    const ushort* X = enz_b + (size_t)b * 512 * 1280 + (size_t)(kh * 256) * 1280 + c;
    float a_se = 0.f, a_pe = 0.f;
#pragma unroll 4
    for (int k = 0; k < 256; k++) {
      const float x = bf2f(X[(size_t)k * 1280]);
      a_se += wse[k] * x;
      a_pe += wpe[k] * x;
    }
    atomicAdd(&wx_se[b * 1280 + c], a_se);
    atomicAdd(&wx_pe[b * 1280 + c], a_pe);
  } else if (f < 352) {
    const int b = f - 320;
    const ushort* X = sub_b + (size_t)b * 128 * 256 + t;
    float a = 0.f;
#pragma unroll 4
    for (int k = 0; k < 128; k++) a += wsum_es[b * 128 + k] * bf2f(X[(size_t)k * 256]);
    wx_es[b * 256 + t] = a;
  } else {
    const int b = f - 352;
    const ushort* X = prod_b + (size_t)b * 128 * 256 + t;
    float a = 0.f;
#pragma unroll 4
    for (int k = 0; k < 128; k++) a += wsum_ep[b * 128 + k] * bf2f(X[(size_t)k * 256]);
    wx_ep[b * 256 + t] = a;
  }
}

// ---------------------------------------------------------------------------
// Kernel 7: out += inv * (wx chunk @ Wv chunk), c-split for occupancy.
// Grid 96. Bias pre-folded into out by prep.
// ---------------------------------------------------------------------------
__global__ __launch_bounds__(256) void out_gemv(
    const float* __restrict__ wx_es, const float* __restrict__ wx_se,
    const float* __restrict__ wx_ep, const float* __restrict__ wx_pe,
    const float* __restrict__ enz_Wv, const float* __restrict__ sub_Wv,
    const float* __restrict__ prod_Wv,
    float* __restrict__ out)
{
  __shared__ float sw[32][64];
  const int f = blockIdx.x, t = threadIdx.x;
  const float* wx; const float* Wv; int Cdim, qoff, nb, cc; float inv;
  if (f < 40)      { wx = wx_se; Wv = sub_Wv;  Cdim = 1280; inv = 1.f / 128.f; qoff = 512;  nb = f & 1;        cc = f >> 1; }
  else if (f < 80) { wx = wx_pe; Wv = prod_Wv; Cdim = 1280; inv = 1.f / 128.f; qoff = 1536; nb = (f - 40) & 1; cc = (f - 40) >> 1; }
  else if (f < 88) { wx = wx_es; Wv = enz_Wv;  Cdim = 256;  inv = 1.f / 512.f; qoff = 0;    nb = (f - 80) & 1; cc = (f - 80) >> 1; }
  else             { wx = wx_ep; Wv = enz_Wv;  Cdim = 256;  inv = 1.f / 512.f; qoff = 1024; nb = (f - 88) & 1; cc = (f - 88) >> 1; }
  const int c0 = cc * 64, n = nb * 256 + t;
#pragma unroll
  for (int i = 0; i < 8; i++) {
    const int idx = t + i * 256, b = idx >> 6, c = idx & 63;
    sw[b][c] = wx[(size_t)b * Cdim + c0 + c];
  }
  __syncthreads();
  float acc[32];
#pragma unroll
  for (int b = 0; b < 32; b++) acc[b] = 0.f;
  for (int c = 0; c < 64; c += 4) {
    const float w0 = Wv[(size_t)(c0 + c) * 512 + n];
    const float w1 = Wv[(size_t)(c0 + c + 1) * 512 + n];
    const float w2 = Wv[(size_t)(c0 + c + 2) * 512 + n];
    const float w3 = Wv[(size_t)(c0 + c + 3) * 512 + n];
#pragma unroll
    for (int b = 0; b < 32; b++) {
      const float4 s = *(const float4*)&sw[b][c];
      acc[b] += s.x * w0 + s.y * w1 + s.z * w2 + s.w * w3;
    }
  }
#pragma unroll
  for (int b = 0; b < 32; b++)
    atomicAdd(&out[(size_t)b * 2048 + qoff + n], acc[b] * inv);
}

// ---------------------------------------------------------------------------
extern "C" void kernel_launch(void* const* d_in, const int* in_sizes, int n_in,
                              void* d_out, int out_size, void* d_ws, size_t ws_size,
                              hipStream_t stream)
{
  (void)in_sizes; (void)n_in; (void)out_size; (void)ws_size;
  const float* enz     = (const float*)d_in[0];   // [32,512,1280]
  const float* sub     = (const float*)d_in[1];   // [32,128,256]
  const float* prod    = (const float*)d_in[2];   // [32,128,256]
  const float* iw      = (const float*)d_in[6];   // [32,128,512]
  const float* enz_Wq  = (const float*)d_in[7];
  const float* enz_bq  = (const float*)d_in[8];
  const float* enz_Wk  = (const float*)d_in[9];
  const float* enz_Wv  = (const float*)d_in[11];
  const float* enz_bv  = (const float*)d_in[12];
  const float* sub_Wq  = (const float*)d_in[13];
  const float* sub_bq  = (const float*)d_in[14];
  const float* sub_Wk  = (const float*)d_in[15];
  const float* sub_Wv  = (const float*)d_in[17];
  const float* sub_bv  = (const float*)d_in[18];
  const float* prod_Wq = (const float*)d_in[19];
  const float* prod_bq = (const float*)d_in[20];
  const float* prod_Wk = (const float*)d_in[21];
  const float* prod_Wv = (const float*)d_in[23];
  const float* prod_bv = (const float*)d_in[24];
  float* out = (float*)d_out;

  char* wsb = (char*)d_ws;
  size_t off = 0;
  auto alloc = [&](size_t bytes) {
    void* p = wsb + off;
    off += (bytes + 255) & ~(size_t)255;
    return p;
  };
  ushort* enz_b   = (ushort*)alloc((size_t)32 * 512 * 1280 * 2);
  ushort* sub_b   = (ushort*)alloc((size_t)32 * 128 * 256 * 2);
  ushort* prod_b  = (ushort*)alloc((size_t)32 * 128 * 256 * 2);
  ushort* eWq_b   = (ushort*)alloc((size_t)1280 * 512 * 2);
  ushort* sWk_b   = (ushort*)alloc((size_t)1280 * 512 * 2);
  ushort* pWk_b   = (ushort*)alloc((size_t)1280 * 512 * 2);
  ushort* eWk_b   = (ushort*)alloc((size_t)256 * 512 * 2);
  ushort* sWq_b   = (ushort*)alloc((size_t)256 * 512 * 2);
  ushort* pWq_b   = (ushort*)alloc((size_t)256 * 512 * 2);
  ushort* W3t     = (ushort*)alloc((size_t)768 * 1280 * 2);
  ushort* Y       = (ushort*)alloc((size_t)16384 * 768 * 2);
  float*  u_s_s   = (float*)alloc(1280 * 4);
  float*  u_p_s   = (float*)alloc(1280 * 4);
  float*  u_e_s   = (float*)alloc(256 * 4);
  float*  t_es    = (float*)alloc(4096 * 4);
  float*  t_ep    = (float*)alloc(4096 * 4);
  float*  t_se    = (float*)alloc(16384 * 4);
  float*  t_pe    = (float*)alloc(16384 * 4);
  float*  Sc_se   = (float*)alloc((size_t)32 * 128 * 512 * 4);
  float*  Sc_pe   = (float*)alloc((size_t)32 * 128 * 512 * 4);
  // zero region (contiguous; sizes are 256B multiples): 147456 floats total
  float* wsum_es = (float*)alloc(4096 * 4);
  float* wsum_ep = (float*)alloc(4096 * 4);
  float* wsum_se = (float*)alloc(16384 * 4);
  float* wsum_pe = (float*)alloc(16384 * 4);
  float* l_se    = (float*)alloc(4096 * 4);
  float* l_pe    = (float*)alloc(4096 * 4);
  float* wx_se   = (float*)alloc(40960 * 4);
  float* wx_pe   = (float*)alloc(40960 * 4);
  float* wx_es   = (float*)alloc(8192 * 4);
  float* wx_ep   = (float*)alloc(8192 * 4);

  static bool ygemm_attr_set = false;
  if (!ygemm_attr_set) {
    hipFuncSetAttribute(reinterpret_cast<const void*>(y_gemm),
                        hipFuncAttributeMaxDynamicSharedMemorySize, 114688);
    ygemm_attr_set = true;
  }

  const dim3 blk(256);

  prep_fused<<<13424, blk, 0, stream>>>(
      enz, sub, prod, enz_b, sub_b, prod_b,
      enz_Wq, enz_Wk, sub_Wq, sub_Wk, prod_Wq, prod_Wk,
      eWq_b, eWk_b, sWq_b, sWk_b, pWq_b, pWk_b,
      enz_bq, sub_bq, prod_bq, enz_bv, sub_bv, prod_bv,
      u_s_s, u_p_s, u_e_s, wsum_es, out);

  fold_w3<<<140, blk, 0, stream>>>(
      eWq_b, eWk_b, sWq_b, sWk_b, pWq_b, pWk_b,
      sub_b, prod_b, enz_b, u_e_s, u_s_s, u_p_s,
      W3t, t_es, t_ep, t_se, t_pe);

  y_gemm<<<256, 512, 114688, stream>>>(enz_b, W3t, Y);

  score_fused<<<512, blk, 0, stream>>>(
      Y, sub_b, prod_b, iw, t_es, t_ep, t_se, t_pe,
      Sc_se, Sc_pe, l_se, l_pe, wsum_es, wsum_ep);

  colsum2<<<256, blk, 0, stream>>>(Sc_se, Sc_pe, l_se, l_pe, wsum_se, wsum_pe);

  wx_fused<<<384, blk, 0, stream>>>(
      wsum_se, wsum_pe, wsum_es, wsum_ep, enz_b, sub_b, prod_b,
      wx_se, wx_pe, wx_es, wx_ep);

  out_gemv<<<96, blk, 0, stream>>>(
      wx_es, wx_se, wx_ep, wx_pe, enz_Wv, sub_Wv, prod_Wv, out);
}